// Round 7
// baseline (48.105 us; speedup 1.0000x reference)
//
#include <hip/hip_runtime.h>

#define BT 64
#define NTHREADS 256

typedef __attribute__((ext_vector_type(8))) __bf16 bf16x8;
typedef __attribute__((ext_vector_type(4))) __bf16 bf16x4;
typedef __attribute__((ext_vector_type(4))) float f32x4;

__device__ __forceinline__ __bf16 f2bf(float f) { return (__bf16)f; }
__device__ __forceinline__ f32x4 ld4(const float* p) { return *(const f32x4*)p; }

// Single fused kernel, LDS-lean for occupancy.
// LDS: W2 [96][72]bf16 (13.8 KB) + Hs [64][72]bf16 (9.2 KB) = 23 KB -> 4 blocks/CU.
// W1 B-fragments stream from global (L2-broadcast) with inline f32->bf16 cvt.
__global__ __launch_bounds__(NTHREADS, 4)
void ncf_one(const int* __restrict__ user_ids, const int* __restrict__ movie_ids,
             const int* __restrict__ genre_ids, const int* __restrict__ offsets,
             const float* __restrict__ user_mem_w, const float* __restrict__ movie_mem_w,
             const float* __restrict__ ue_gmf, const float* __restrict__ me_gmf,
             const float* __restrict__ ge_gmf,
             const float* __restrict__ ue_mlp, const float* __restrict__ me_mlp,
             const float* __restrict__ ge_mlp,
             const float* __restrict__ w1, const float* __restrict__ b1,
             const float* __restrict__ w2, const float* __restrict__ b2,
             const float* __restrict__ w_out, const float* __restrict__ b_out,
             float* __restrict__ out, int Btot, int totG)
{
    __shared__ __bf16 WL2[96 * 72];    // row stride 144 B
    __shared__ __bf16 Hs[64 * 72];

    const int tid  = threadIdx.x;
    const int lane = tid & 63;
    const int wid  = tid >> 6;
    const int lr   = lane & 15;
    const int lg   = lane >> 4;
    const int e0   = blockIdx.x * BT;

    // ---- w2 convert into LDS (L2-hot broadcast reads) ----
    #pragma unroll
    for (int j = 0; j < 6; ++j) {                // w2: 1536 f32x4, rows of 16
        const int v = tid + j * 256;
        const int r = v >> 4, c4 = v & 15;
        f32x4 a = ld4(w2 + (size_t)v * 4);
        bf16x4 t; t[0]=f2bf(a[0]); t[1]=f2bf(a[1]); t[2]=f2bf(a[2]); t[3]=f2bf(a[3]);
        *(bf16x4*)&WL2[r * 72 + c4 * 4] = t;
    }

    // ---- per-element gather (4 lanes/element) ----
    const int erow = wid * 16 + lr;
    const int gidx = min(e0 + erow, Btot - 1);
    const int u    = user_ids[gidx];
    const int mv   = movie_ids[gidx];
    const int gs   = offsets[gidx];
    const int gend = (gidx + 1 < Btot) ? offsets[gidx + 1] : totG;
    const int cnt  = gend - gs;
    const float inv = 1.0f / (float)(cnt > 0 ? cnt : 1);

    // single genre pass: gmf chunks gg0/gg1, mlp chunks gm0/gm1
    f32x4 gg0 = {0.f,0.f,0.f,0.f}, gg1 = {0.f,0.f,0.f,0.f};
    f32x4 gm0 = {0.f,0.f,0.f,0.f}, gm1 = {0.f,0.f,0.f,0.f};
    for (int i = gs; i < gend; ++i) {
        const int g = genre_ids[i];
        const float* pg = ge_gmf + (size_t)g * 32 + 4 * lg;
        gg0 += ld4(pg);
        gg1 += ld4(pg + 16);
        const float* pm = ge_mlp + (size_t)g * 32 + 8 * lg;
        gm0 += ld4(pm);
        gm1 += ld4(pm + 4);
    }

    // A-fragments: lane (lr,lg) holds X[erow][kt*32 + lg*8 .. +7]
    bf16x8 fr[6];
    {
        const float* up = ue_mlp + (size_t)u * 96 + lg * 8;
        const float* mp = me_mlp + (size_t)mv * 64 + lg * 8;
        #pragma unroll
        for (int kt = 0; kt < 3; ++kt) {
            f32x4 a = ld4(up + kt * 32), b = ld4(up + kt * 32 + 4);
            bf16x8 t;
            t[0]=f2bf(a[0]); t[1]=f2bf(a[1]); t[2]=f2bf(a[2]); t[3]=f2bf(a[3]);
            t[4]=f2bf(b[0]); t[5]=f2bf(b[1]); t[6]=f2bf(b[2]); t[7]=f2bf(b[3]);
            fr[kt] = t;
        }
        #pragma unroll
        for (int kt = 0; kt < 2; ++kt) {
            f32x4 a = ld4(mp + kt * 32), b = ld4(mp + kt * 32 + 4);
            bf16x8 t;
            t[0]=f2bf(a[0]); t[1]=f2bf(a[1]); t[2]=f2bf(a[2]); t[3]=f2bf(a[3]);
            t[4]=f2bf(b[0]); t[5]=f2bf(b[1]); t[6]=f2bf(b[2]); t[7]=f2bf(b[3]);
            fr[3 + kt] = t;
        }
        bf16x8 t;
        t[0]=f2bf(gm0[0]*inv); t[1]=f2bf(gm0[1]*inv); t[2]=f2bf(gm0[2]*inv); t[3]=f2bf(gm0[3]*inv);
        t[4]=f2bf(gm1[0]*inv); t[5]=f2bf(gm1[1]*inv); t[6]=f2bf(gm1[2]*inv); t[7]=f2bf(gm1[3]*inv);
        fr[5] = t;
    }

    // GMF dot (f32 exact)
    float pval;
    {
        float s = 0.f;
        #pragma unroll
        for (int j = 0; j < 4; ++j) {
            const int d = 4 * lg + 16 * j;
            f32x4 ug = ld4(ue_gmf + (size_t)u * 96 + d);
            f32x4 mg = ld4(me_gmf + (size_t)mv * 64 + d);
            f32x4 wo = ld4(w_out + d);
            s += ug[0]*mg[0]*wo[0] + ug[1]*mg[1]*wo[1] + ug[2]*mg[2]*wo[2] + ug[3]*mg[3]*wo[3];
        }
        {
            const int d = 64 + 4 * lg;
            f32x4 ug = ld4(ue_gmf + (size_t)u * 96 + d);
            f32x4 wo = ld4(w_out + d);
            s += ug[0]*gg0[0]*inv*wo[0] + ug[1]*gg0[1]*inv*wo[1]
               + ug[2]*gg0[2]*inv*wo[2] + ug[3]*gg0[3]*inv*wo[3];
        }
        {
            const int d = 80 + 4 * lg;
            f32x4 ug = ld4(ue_gmf + (size_t)u * 96 + d);
            f32x4 wo = ld4(w_out + d);
            s += ug[0]*gg1[0]*inv*wo[0] + ug[1]*gg1[1]*inv*wo[1]
               + ug[2]*gg1[2]*inv*wo[2] + ug[3]*gg1[3]*inv*wo[3];
        }
        if (lg == 0) s += user_mem_w[u] + movie_mem_w[mv] + b_out[0];
        s += __shfl_xor(s, 16);
        s += __shfl_xor(s, 32);
        pval = s;
    }

    __syncthreads();   // WL2 ready

    // ---- GEMM1: X[64x192] @ W1^T -> H[64x64], B-frags streamed from global ----
    f32x4 acc1[4] = {};
    #pragma unroll
    for (int kt = 0; kt < 6; ++kt) {
        // batch the 8 loads for this kt before converting (L2-hit latency overlap)
        f32x4 wa[4], wb[4];
        #pragma unroll
        for (int nt = 0; nt < 4; ++nt) {
            const float* wp = w1 + (size_t)(nt * 16 + lr) * 192 + kt * 32 + lg * 8;
            wa[nt] = ld4(wp);
            wb[nt] = ld4(wp + 4);
        }
        #pragma unroll
        for (int nt = 0; nt < 4; ++nt) {
            bf16x8 bw;
            bw[0]=f2bf(wa[nt][0]); bw[1]=f2bf(wa[nt][1]); bw[2]=f2bf(wa[nt][2]); bw[3]=f2bf(wa[nt][3]);
            bw[4]=f2bf(wb[nt][0]); bw[5]=f2bf(wb[nt][1]); bw[6]=f2bf(wb[nt][2]); bw[7]=f2bf(wb[nt][3]);
            acc1[nt] = __builtin_amdgcn_mfma_f32_16x16x32_bf16(fr[kt], bw, acc1[nt], 0, 0, 0);
        }
    }
    #pragma unroll
    for (int nt = 0; nt < 4; ++nt) {
        const float bv = b1[nt * 16 + lr];
        #pragma unroll
        for (int r = 0; r < 4; ++r) {
            float v = acc1[nt][r] + bv;
            v = v > 0.f ? v : 0.f;
            Hs[(wid * 16 + lg * 4 + r) * 72 + nt * 16 + lr] = f2bf(v);
        }
    }
    __syncthreads();

    // ---- GEMM2: H[64x64] @ W2^T -> [64x96], fused epilogue ----
    f32x4 acc2[6] = {};
    #pragma unroll
    for (int kt = 0; kt < 2; ++kt) {
        bf16x8 av = *(const bf16x8*)&Hs[(wid * 16 + lr) * 72 + kt * 32 + lg * 8];
        #pragma unroll
        for (int nt = 0; nt < 6; ++nt) {
            bf16x8 bw = *(const bf16x8*)&WL2[(nt * 16 + lr) * 72 + kt * 32 + lg * 8];
            acc2[nt] = __builtin_amdgcn_mfma_f32_16x16x32_bf16(av, bw, acc2[nt], 0, 0, 0);
        }
    }

    float s0 = 0.f, s1 = 0.f, s2 = 0.f, s3 = 0.f;
    #pragma unroll
    for (int nt = 0; nt < 6; ++nt) {
        const int col = nt * 16 + lr;
        const float b2v = b2[col];
        const float wo  = w_out[96 + col];
        float v;
        v = acc2[nt][0] + b2v; v = v > 0.f ? v : 0.f; s0 += v * wo;
        v = acc2[nt][1] + b2v; v = v > 0.f ? v : 0.f; s1 += v * wo;
        v = acc2[nt][2] + b2v; v = v > 0.f ? v : 0.f; s2 += v * wo;
        v = acc2[nt][3] + b2v; v = v > 0.f ? v : 0.f; s3 += v * wo;
    }
    #pragma unroll
    for (int mask = 1; mask <= 8; mask <<= 1) {
        s0 += __shfl_xor(s0, mask);
        s1 += __shfl_xor(s1, mask);
        s2 += __shfl_xor(s2, mask);
        s3 += __shfl_xor(s3, mask);
    }
    const float p0 = __shfl(pval, lg * 4 + 0);
    const float p1 = __shfl(pval, lg * 4 + 1);
    const float p2 = __shfl(pval, lg * 4 + 2);
    const float p3 = __shfl(pval, lg * 4 + 3);

    if (lr == 0) {
        const int rowb = e0 + wid * 16 + lg * 4;
        if (rowb + 0 < Btot) out[rowb + 0] = p0 + s0;
        if (rowb + 1 < Btot) out[rowb + 1] = p1 + s1;
        if (rowb + 2 < Btot) out[rowb + 2] = p2 + s2;
        if (rowb + 3 < Btot) out[rowb + 3] = p3 + s3;
    }
}

extern "C" void kernel_launch(void* const* d_in, const int* in_sizes, int n_in,
                              void* d_out, int out_size, void* d_ws, size_t ws_size,
                              hipStream_t stream) {
    const int*   user_ids    = (const int*)d_in[0];
    const int*   movie_ids   = (const int*)d_in[1];
    const int*   genre_ids   = (const int*)d_in[2];
    const int*   offsets     = (const int*)d_in[3];
    const float* user_mem_w  = (const float*)d_in[4];
    const float* movie_mem_w = (const float*)d_in[5];
    const float* ue_gmf      = (const float*)d_in[6];
    const float* me_gmf      = (const float*)d_in[7];
    const float* ge_gmf      = (const float*)d_in[8];
    const float* ue_mlp      = (const float*)d_in[9];
    const float* me_mlp      = (const float*)d_in[10];
    const float* ge_mlp      = (const float*)d_in[11];
    const float* w1          = (const float*)d_in[12];
    const float* b1          = (const float*)d_in[13];
    const float* w2          = (const float*)d_in[14];
    const float* b2          = (const float*)d_in[15];
    const float* w_out       = (const float*)d_in[16];
    const float* b_out       = (const float*)d_in[17];

    const int Btot = in_sizes[0];
    const int totG = in_sizes[2];

    const int grid = (Btot + BT - 1) / BT;
    ncf_one<<<grid, NTHREADS, 0, stream>>>(
        user_ids, movie_ids, genre_ids, offsets,
        user_mem_w, movie_mem_w,
        ue_gmf, me_gmf, ge_gmf,
        ue_mlp, me_mlp, ge_mlp,
        w1, b1, w2, b2, w_out, b_out,
        (float*)d_out, Btot, totG);
}

// Round 8
// 28.267 us; speedup vs baseline: 1.7018x; 1.7018x over previous
//
#include <hip/hip_runtime.h>

#define BT 64
#define NTHREADS 256

typedef __attribute__((ext_vector_type(8))) __bf16 bf16x8;
typedef __attribute__((ext_vector_type(4))) __bf16 bf16x4;
typedef __attribute__((ext_vector_type(4))) float f32x4;

__device__ __forceinline__ __bf16 f2bf(float f) { return (__bf16)f; }
__device__ __forceinline__ f32x4 ld4(const float* p) { return *(const f32x4*)p; }

// Single fused kernel. LDS: SA (WL1 [64][200] bf16, reused as Hs [64][72] after
// GEMM1) + WL2 [96][72] = 39.4 KB -> 4 blocks/CU. W1/W2 converted per-block
// into LDS (L2-broadcast reads, hidden under gather latency).
__global__ __launch_bounds__(NTHREADS, 4)
void ncf_one(const int* __restrict__ user_ids, const int* __restrict__ movie_ids,
             const int* __restrict__ genre_ids, const int* __restrict__ offsets,
             const float* __restrict__ user_mem_w, const float* __restrict__ movie_mem_w,
             const float* __restrict__ ue_gmf, const float* __restrict__ me_gmf,
             const float* __restrict__ ge_gmf,
             const float* __restrict__ ue_mlp, const float* __restrict__ me_mlp,
             const float* __restrict__ ge_mlp,
             const float* __restrict__ w1, const float* __restrict__ b1,
             const float* __restrict__ w2, const float* __restrict__ b2,
             const float* __restrict__ w_out, const float* __restrict__ b_out,
             float* __restrict__ out, int Btot, int totG)
{
    __shared__ __bf16 SA[64 * 200];    // WL1 during GEMM1; Hs afterwards
    __shared__ __bf16 WL2[96 * 72];    // row stride 144 B

    const int tid  = threadIdx.x;
    const int lane = tid & 63;
    const int wid  = tid >> 6;
    const int lr   = lane & 15;
    const int lg   = lane >> 4;
    const int e0   = blockIdx.x * BT;

    // ---- weight convert into LDS (L2-hot broadcast reads) ----
    #pragma unroll
    for (int j = 0; j < 12; ++j) {               // w1: 3072 f32x4, rows of 48
        const int v = tid + j * 256;
        const int r = v / 48, c4 = v % 48;
        f32x4 a = ld4(w1 + (size_t)v * 4);
        bf16x4 t; t[0]=f2bf(a[0]); t[1]=f2bf(a[1]); t[2]=f2bf(a[2]); t[3]=f2bf(a[3]);
        *(bf16x4*)&SA[r * 200 + c4 * 4] = t;
    }
    #pragma unroll
    for (int j = 0; j < 6; ++j) {                // w2: 1536 f32x4, rows of 16
        const int v = tid + j * 256;
        const int r = v >> 4, c4 = v & 15;
        f32x4 a = ld4(w2 + (size_t)v * 4);
        bf16x4 t; t[0]=f2bf(a[0]); t[1]=f2bf(a[1]); t[2]=f2bf(a[2]); t[3]=f2bf(a[3]);
        *(bf16x4*)&WL2[r * 72 + c4 * 4] = t;
    }

    // ---- per-element gather (4 lanes/element) ----
    const int erow = wid * 16 + lr;
    const int gidx = min(e0 + erow, Btot - 1);
    const int u    = user_ids[gidx];
    const int mv   = movie_ids[gidx];
    const int gs   = offsets[gidx];
    const int gend = (gidx + 1 < Btot) ? offsets[gidx + 1] : totG;
    const int cnt  = gend - gs;
    const float inv = 1.0f / (float)(cnt > 0 ? cnt : 1);

    // single genre pass: gmf chunks gg0/gg1, mlp chunks gm0/gm1
    f32x4 gg0 = {0.f,0.f,0.f,0.f}, gg1 = {0.f,0.f,0.f,0.f};
    f32x4 gm0 = {0.f,0.f,0.f,0.f}, gm1 = {0.f,0.f,0.f,0.f};
    for (int i = gs; i < gend; ++i) {
        const int g = genre_ids[i];
        const float* pg = ge_gmf + (size_t)g * 32 + 4 * lg;
        gg0 += ld4(pg);
        gg1 += ld4(pg + 16);
        const float* pm = ge_mlp + (size_t)g * 32 + 8 * lg;
        gm0 += ld4(pm);
        gm1 += ld4(pm + 4);
    }

    // A-fragments: lane (lr,lg) holds X[erow][kt*32 + lg*8 .. +7]
    bf16x8 fr[6];
    {
        const float* up = ue_mlp + (size_t)u * 96 + lg * 8;
        const float* mp = me_mlp + (size_t)mv * 64 + lg * 8;
        #pragma unroll
        for (int kt = 0; kt < 3; ++kt) {
            f32x4 a = ld4(up + kt * 32), b = ld4(up + kt * 32 + 4);
            bf16x8 t;
            t[0]=f2bf(a[0]); t[1]=f2bf(a[1]); t[2]=f2bf(a[2]); t[3]=f2bf(a[3]);
            t[4]=f2bf(b[0]); t[5]=f2bf(b[1]); t[6]=f2bf(b[2]); t[7]=f2bf(b[3]);
            fr[kt] = t;
        }
        #pragma unroll
        for (int kt = 0; kt < 2; ++kt) {
            f32x4 a = ld4(mp + kt * 32), b = ld4(mp + kt * 32 + 4);
            bf16x8 t;
            t[0]=f2bf(a[0]); t[1]=f2bf(a[1]); t[2]=f2bf(a[2]); t[3]=f2bf(a[3]);
            t[4]=f2bf(b[0]); t[5]=f2bf(b[1]); t[6]=f2bf(b[2]); t[7]=f2bf(b[3]);
            fr[3 + kt] = t;
        }
        bf16x8 t;
        t[0]=f2bf(gm0[0]*inv); t[1]=f2bf(gm0[1]*inv); t[2]=f2bf(gm0[2]*inv); t[3]=f2bf(gm0[3]*inv);
        t[4]=f2bf(gm1[0]*inv); t[5]=f2bf(gm1[1]*inv); t[6]=f2bf(gm1[2]*inv); t[7]=f2bf(gm1[3]*inv);
        fr[5] = t;
    }

    // GMF dot (f32 exact)
    float pval;
    {
        float s = 0.f;
        #pragma unroll
        for (int j = 0; j < 4; ++j) {
            const int d = 4 * lg + 16 * j;
            f32x4 ug = ld4(ue_gmf + (size_t)u * 96 + d);
            f32x4 mg = ld4(me_gmf + (size_t)mv * 64 + d);
            f32x4 wo = ld4(w_out + d);
            s += ug[0]*mg[0]*wo[0] + ug[1]*mg[1]*wo[1] + ug[2]*mg[2]*wo[2] + ug[3]*mg[3]*wo[3];
        }
        {
            const int d = 64 + 4 * lg;
            f32x4 ug = ld4(ue_gmf + (size_t)u * 96 + d);
            f32x4 wo = ld4(w_out + d);
            s += ug[0]*gg0[0]*inv*wo[0] + ug[1]*gg0[1]*inv*wo[1]
               + ug[2]*gg0[2]*inv*wo[2] + ug[3]*gg0[3]*inv*wo[3];
        }
        {
            const int d = 80 + 4 * lg;
            f32x4 ug = ld4(ue_gmf + (size_t)u * 96 + d);
            f32x4 wo = ld4(w_out + d);
            s += ug[0]*gg1[0]*inv*wo[0] + ug[1]*gg1[1]*inv*wo[1]
               + ug[2]*gg1[2]*inv*wo[2] + ug[3]*gg1[3]*inv*wo[3];
        }
        if (lg == 0) s += user_mem_w[u] + movie_mem_w[mv] + b_out[0];
        s += __shfl_xor(s, 16);
        s += __shfl_xor(s, 32);
        pval = s;
    }

    __syncthreads();   // barrier 1: WL1/WL2 ready

    // ---- GEMM1: X[64x192] @ W1^T -> acc1 ----
    f32x4 acc1[4] = {};
    #pragma unroll
    for (int kt = 0; kt < 6; ++kt) {
        #pragma unroll
        for (int nt = 0; nt < 4; ++nt) {
            bf16x8 bw = *(const bf16x8*)&SA[(nt * 16 + lr) * 200 + kt * 32 + lg * 8];
            acc1[nt] = __builtin_amdgcn_mfma_f32_16x16x32_bf16(fr[kt], bw, acc1[nt], 0, 0, 0);
        }
    }

    __syncthreads();   // barrier 2: all waves done reading WL1 -> SA reusable as Hs

    // bias + relu -> Hs (in SA)
    #pragma unroll
    for (int nt = 0; nt < 4; ++nt) {
        const float bv = b1[nt * 16 + lr];
        #pragma unroll
        for (int r = 0; r < 4; ++r) {
            float v = acc1[nt][r] + bv;
            v = v > 0.f ? v : 0.f;
            SA[(wid * 16 + lg * 4 + r) * 72 + nt * 16 + lr] = f2bf(v);
        }
    }
    __syncthreads();   // barrier 3: Hs visible

    // ---- GEMM2: H[64x64] @ W2^T -> [64x96], fused epilogue ----
    f32x4 acc2[6] = {};
    #pragma unroll
    for (int kt = 0; kt < 2; ++kt) {
        bf16x8 av = *(const bf16x8*)&SA[(wid * 16 + lr) * 72 + kt * 32 + lg * 8];
        #pragma unroll
        for (int nt = 0; nt < 6; ++nt) {
            bf16x8 bw = *(const bf16x8*)&WL2[(nt * 16 + lr) * 72 + kt * 32 + lg * 8];
            acc2[nt] = __builtin_amdgcn_mfma_f32_16x16x32_bf16(av, bw, acc2[nt], 0, 0, 0);
        }
    }

    float s0 = 0.f, s1 = 0.f, s2 = 0.f, s3 = 0.f;
    #pragma unroll
    for (int nt = 0; nt < 6; ++nt) {
        const int col = nt * 16 + lr;
        const float b2v = b2[col];
        const float wo  = w_out[96 + col];
        float v;
        v = acc2[nt][0] + b2v; v = v > 0.f ? v : 0.f; s0 += v * wo;
        v = acc2[nt][1] + b2v; v = v > 0.f ? v : 0.f; s1 += v * wo;
        v = acc2[nt][2] + b2v; v = v > 0.f ? v : 0.f; s2 += v * wo;
        v = acc2[nt][3] + b2v; v = v > 0.f ? v : 0.f; s3 += v * wo;
    }
    #pragma unroll
    for (int mask = 1; mask <= 8; mask <<= 1) {
        s0 += __shfl_xor(s0, mask);
        s1 += __shfl_xor(s1, mask);
        s2 += __shfl_xor(s2, mask);
        s3 += __shfl_xor(s3, mask);
    }
    const float p0 = __shfl(pval, lg * 4 + 0);
    const float p1 = __shfl(pval, lg * 4 + 1);
    const float p2 = __shfl(pval, lg * 4 + 2);
    const float p3 = __shfl(pval, lg * 4 + 3);

    if (lr == 0) {
        const int rowb = e0 + wid * 16 + lg * 4;
        if (rowb + 0 < Btot) out[rowb + 0] = p0 + s0;
        if (rowb + 1 < Btot) out[rowb + 1] = p1 + s1;
        if (rowb + 2 < Btot) out[rowb + 2] = p2 + s2;
        if (rowb + 3 < Btot) out[rowb + 3] = p3 + s3;
    }
}

extern "C" void kernel_launch(void* const* d_in, const int* in_sizes, int n_in,
                              void* d_out, int out_size, void* d_ws, size_t ws_size,
                              hipStream_t stream) {
    const int*   user_ids    = (const int*)d_in[0];
    const int*   movie_ids   = (const int*)d_in[1];
    const int*   genre_ids   = (const int*)d_in[2];
    const int*   offsets     = (const int*)d_in[3];
    const float* user_mem_w  = (const float*)d_in[4];
    const float* movie_mem_w = (const float*)d_in[5];
    const float* ue_gmf      = (const float*)d_in[6];
    const float* me_gmf      = (const float*)d_in[7];
    const float* ge_gmf      = (const float*)d_in[8];
    const float* ue_mlp      = (const float*)d_in[9];
    const float* me_mlp      = (const float*)d_in[10];
    const float* ge_mlp      = (const float*)d_in[11];
    const float* w1          = (const float*)d_in[12];
    const float* b1          = (const float*)d_in[13];
    const float* w2          = (const float*)d_in[14];
    const float* b2          = (const float*)d_in[15];
    const float* w_out       = (const float*)d_in[16];
    const float* b_out       = (const float*)d_in[17];

    const int Btot = in_sizes[0];
    const int totG = in_sizes[2];

    const int grid = (Btot + BT - 1) / BT;
    ncf_one<<<grid, NTHREADS, 0, stream>>>(
        user_ids, movie_ids, genre_ids, offsets,
        user_mem_w, movie_mem_w,
        ue_gmf, me_gmf, ge_gmf,
        ue_mlp, me_mlp, ge_mlp,
        w1, b1, w2, b2, w_out, b_out,
        (float*)d_out, Btot, totG);
}